// Round 1
// 1204.227 us; speedup vs baseline: 1.1530x; 1.1530x over previous
//
#include <hip/hip_runtime.h>
#include <hip/hip_bf16.h>
#include <cstdint>
#include <cstddef>

typedef unsigned short u16;
typedef __attribute__((ext_vector_type(8))) __bf16 bf16x8;
typedef __attribute__((ext_vector_type(4))) float floatx4;

#define B_ 8
#define S_ 2048
#define D_ 1024
#define H_ 4096
#define E_ 8

__device__ __forceinline__ u16 f2bf(float f) {
    union { float f; unsigned u; } c; c.f = f;
    return (u16)((c.u + 0x7fffu + ((c.u >> 16) & 1u)) >> 16);  // RNE, finite inputs
}

__device__ __forceinline__ void gload16(const void* g, void* l) {
    __builtin_amdgcn_global_load_lds((__attribute__((address_space(1))) void*)(g),
                                     (__attribute__((address_space(3))) void*)(l),
                                     16, 0, 0);
}

// ===================== old 128x128 2-phase helpers (tier-C fallback) =====================
__device__ __forceinline__ void stage(const u16* gbase, int ld, u16* lds, int tid) {
    int wid = tid >> 6;
#pragma unroll
    for (int q = 0; q < 4; ++q) {
        int j = q * 256 + tid;
        int r = j >> 3;
        int c = (j & 7) ^ (r & 7);
        gload16(gbase + (size_t)r * ld + c * 8,
                lds + (size_t)(q * 256 + wid * 64) * 8);
    }
}

__device__ __forceinline__ void stageF(const float* gbase, int ld, u16* lds, int tid) {
#pragma unroll
    for (int q = 0; q < 4; ++q) {
        int j = q * 256 + tid;
        int r = j >> 3;
        int c = (j & 7) ^ (r & 7);
        const float* src = gbase + (size_t)r * ld + c * 8;
        u16 tmp[8];
#pragma unroll
        for (int i = 0; i < 8; ++i) tmp[i] = f2bf(src[i]);
        *(uint4*)(lds + (size_t)j * 8) = *(uint4*)tmp;
    }
}

__device__ __forceinline__ void stageKTF(const float* gbase, int ld, u16* lds, int tid) {
#pragma unroll
    for (int q = 0; q < 4; ++q) {
        int g = q * 256 + tid;
        int k = g >> 4;
        int nc = g & 15;
        const float* src = gbase + (size_t)k * ld + nc * 8;
        int kc = k >> 3, kl = k & 7;
#pragma unroll
        for (int i = 0; i < 8; ++i) {
            int n = nc * 8 + i;
            lds[(((n << 3) + (kc ^ (n & 7))) << 3) + kl] = f2bf(src[i]);
        }
    }
}

__device__ __forceinline__ bf16x8 fragld(const u16* lds, int row, int c) {
    return *(const bf16x8*)(lds + (((row << 3) + (c ^ (row & 7))) << 3));
}

// ---------------- gate (fp32 throughout) ----------------
__global__ void mean1_kernel(const float* __restrict__ x, float* __restrict__ part) {
    int d = (blockIdx.x & 3) * 256 + threadIdx.x;
    int b = blockIdx.x >> 2;
    int sc = blockIdx.y;
    const float* p = x + (size_t)b * S_ * D_ + (size_t)sc * 256 * D_ + d;
    float s = 0.f;
#pragma unroll 8
    for (int i = 0; i < 256; ++i) s += p[(size_t)i * D_];
    part[((size_t)b * 8 + sc) * D_ + d] = s;
}

__global__ void mean2_kernel(const float* __restrict__ part, float* __restrict__ ri) {
    int d = (blockIdx.x & 3) * 256 + threadIdx.x;
    int b = blockIdx.x >> 2;
    float s = 0.f;
#pragma unroll
    for (int i = 0; i < 8; ++i) s += part[((size_t)b * 8 + i) * D_ + d];
    ri[b * D_ + d] = s * (1.0f / S_);
}

__global__ void gate1_kernel(const float* __restrict__ ri, const float* __restrict__ Wg1,
                             const float* __restrict__ bg1, float* __restrict__ gh) {
    int j = (blockIdx.x & 3) * 256 + threadIdx.x;
    int b = blockIdx.x >> 2;
    const float* r = ri + b * D_;
    float acc = 0.f;
    for (int i = 0; i < D_; ++i) acc += r[i] * Wg1[(size_t)i * D_ + j];
    acc += bg1[j];
    gh[b * D_ + j] = acc / (1.f + expf(-acc));
}

__global__ void gate2_kernel(const float* __restrict__ gh, const float* __restrict__ Wg2,
                             const float* __restrict__ bg2, float* __restrict__ wgate,
                             int* __restrict__ eidx, float* __restrict__ out) {
    __shared__ float lg[B_ * E_];
    int t = threadIdx.x;  // 64 threads: (b,e) pairs
    int b = t >> 3, e = t & 7;
    const float* g = gh + b * D_;
    float acc = 0.f;
    for (int i = 0; i < D_; ++i) acc += g[i] * Wg2[(size_t)i * E_ + e];
    acc += bg2[e];
    lg[t] = acc;
    __syncthreads();
    if (t < B_) {
        float l0 = -1e30f, l1 = -1e30f; int i0 = 0, i1 = 0;
        for (int ee = 0; ee < E_; ++ee) {
            float v = lg[t * E_ + ee];
            if (v > l0) { l1 = l0; i1 = i0; l0 = v; i0 = ee; }
            else if (v > l1) { l1 = v; i1 = ee; }
        }
        float e1 = expf(l1 - l0);
        float w0 = 1.f / (1.f + e1), w1 = e1 / (1.f + e1);
        wgate[t * 2] = w0; wgate[t * 2 + 1] = w1;
        eidx[t * 2] = i0;  eidx[t * 2 + 1] = i1;
        float* ow = out + (size_t)B_ * S_ * D_;        // tail: topk_w then topk_idx
        ow[t * 2] = w0;              ow[t * 2 + 1] = w1;
        ow[16 + t * 2] = (float)i0;  ow[16 + t * 2 + 1] = (float)i1;
    }
}

// ---------------- converters (tier A) ----------------
__global__ void convx_kernel(const float* __restrict__ in, u16* __restrict__ out) {
    size_t i = ((size_t)blockIdx.x * 256 + threadIdx.x) * 8;
    u16 tmp[8];
#pragma unroll
    for (int j = 0; j < 8; ++j) tmp[j] = f2bf(in[i + j]);
    *(uint4*)(out + i) = *(uint4*)tmp;
}

// in fp32 [E][R][C] -> out bf16 [E][C][R]
__global__ __launch_bounds__(256) void convT_kernel(const float* __restrict__ in,
                                                    u16* __restrict__ out,
                                                    int R, int C) {
    __shared__ __align__(16) u16 T[64][72];
    int e = blockIdx.z;
    const float* ine = in + (size_t)e * R * C;
    u16* oute = out + (size_t)e * R * C;
    int r0 = blockIdx.y * 64, c0 = blockIdx.x * 64;
    int tid = threadIdx.x;
#pragma unroll
    for (int q = 0; q < 2; ++q) {
        int j = q * 256 + tid;
        int r = j >> 3, ch = j & 7;
        const float* src = ine + (size_t)(r0 + r) * C + c0 + ch * 8;
        u16 tmp[8];
#pragma unroll
        for (int i = 0; i < 8; ++i) tmp[i] = f2bf(src[i]);
        *(uint4*)&T[r][ch * 8] = *(uint4*)tmp;
    }
    __syncthreads();
#pragma unroll
    for (int q = 0; q < 2; ++q) {
        int j = q * 256 + tid;
        int orow = j >> 3, och = j & 7;
        uint4 v; u16* pv = (u16*)&v;
#pragma unroll
        for (int i = 0; i < 8; ++i) pv[i] = T[och * 8 + i][orow];
        *(uint4*)(oute + (size_t)(c0 + orow) * R + r0 + och * 8) = v;
    }
}

// ===================== 256x256 8-phase GEMMs (tier A) =====================
// LDS ring of 4 K-tiles (BK=32). Slot layout: granule(row,c) = row*4 + (c ^ ((row>>1)&3)),
// 8 bf16 per granule. Staged via global_load_lds with pre-swizzled global source.
// Pipeline: while computing kt, stage kt+3 (slot vacated by kt-1; issue order after the
// end-of-(kt-1) barrier makes overwrite-before-read impossible). vmcnt(8) at each K-tile
// boundary guarantees kt+1 landed (outstanding = kt+2 + kt+3 = 8 loads/wave).

#define VMWAIT(N) do { \
    if ((N) == 8) asm volatile("s_waitcnt vmcnt(8)" ::: "memory"); \
    else if ((N) == 4) asm volatile("s_waitcnt vmcnt(4)" ::: "memory"); \
    else if ((N) == 0) asm volatile("s_waitcnt vmcnt(0)" ::: "memory"); \
} while (0)

// one K-tile = 2 phases; STAGEA/STAGEB are statements issuing the 2 half-tile loads each.
#define KTILE(kt, STAGEA, STAGEB, VM) do { \
    const u16* sA = lA[(kt) & 3]; const u16* sB = lB[(kt) & 3]; \
    bf16x8 af[4], bfr[4]; \
    _Pragma("unroll") for (int t = 0; t < 4; ++t) af[t] = *(const bf16x8*)(sA + offA[0][t]); \
    _Pragma("unroll") for (int t = 0; t < 4; ++t) bfr[t] = *(const bf16x8*)(sB + offB[t]); \
    STAGEA; \
    __builtin_amdgcn_s_barrier(); \
    asm volatile("s_waitcnt lgkmcnt(0)" ::: "memory"); \
    __builtin_amdgcn_sched_barrier(0); \
    __builtin_amdgcn_s_setprio(1); \
    _Pragma("unroll") for (int mt = 0; mt < 4; ++mt) \
        _Pragma("unroll") for (int nt = 0; nt < 4; ++nt) \
            acc[mt][nt] = __builtin_amdgcn_mfma_f32_16x16x32_bf16(af[mt], bfr[nt], acc[mt][nt], 0, 0, 0); \
    __builtin_amdgcn_s_setprio(0); \
    __builtin_amdgcn_s_barrier(); \
    _Pragma("unroll") for (int t = 0; t < 4; ++t) af[t] = *(const bf16x8*)(sA + offA[1][t]); \
    STAGEB; \
    __builtin_amdgcn_s_barrier(); \
    asm volatile("s_waitcnt lgkmcnt(0)" ::: "memory"); \
    __builtin_amdgcn_sched_barrier(0); \
    __builtin_amdgcn_s_setprio(1); \
    _Pragma("unroll") for (int mt = 0; mt < 4; ++mt) \
        _Pragma("unroll") for (int nt = 0; nt < 4; ++nt) \
            acc[4 + mt][nt] = __builtin_amdgcn_mfma_f32_16x16x32_bf16(af[mt], bfr[nt], acc[4 + mt][nt], 0, 0, 0); \
    __builtin_amdgcn_s_setprio(0); \
    VMWAIT(VM); \
    __builtin_amdgcn_s_barrier(); \
} while (0)

// shared per-thread setup for both 8p kernels
#define SETUP_8P(LDBYTES) \
    const int tid = threadIdx.x, lane = tid & 63, wid = tid >> 6; \
    const int wr = wid >> 2, wc = wid & 3, lr = lane & 15, quad = lane >> 4; \
    int soff[2]; \
    _Pragma("unroll") for (int h = 0; h < 2; ++h) { \
        int g = h * 512 + tid; \
        int r = g >> 2, c = (g & 3) ^ ((g >> 3) & 3); \
        soff[h] = r * (LDBYTES) + c * 16; \
    } \
    const int ldst = wid * 64 * 8; \
    int offA[2][4], offB[4]; \
    _Pragma("unroll") for (int mh = 0; mh < 2; ++mh) \
        _Pragma("unroll") for (int t = 0; t < 4; ++t) { \
            int row = wr * 128 + mh * 64 + t * 16 + lr; \
            offA[mh][t] = (row * 4 + (quad ^ ((row >> 1) & 3))) * 8; \
        } \
    _Pragma("unroll") for (int t = 0; t < 4; ++t) { \
        int row = wc * 64 + t * 16 + lr; \
        offB[t] = (row * 4 + (quad ^ ((row >> 1) & 3))) * 8; \
    } \
    floatx4 acc[8][4] = {};

// GEMM1: hbuf[lp] = wk * silu(xb[b] @ W1T[e]^T + b1[e]);  A,B both row-major k-contig, ld=D_
__global__ __launch_bounds__(512) void gemm1_8p(
    const u16* __restrict__ A, const u16* __restrict__ Bw,
    const float* __restrict__ b1, const int* __restrict__ eidx,
    const float* __restrict__ wgate, u16* __restrict__ hbuf,
    int s0, int hRows) {
    __shared__ __align__(16) u16 lA[4][8192];
    __shared__ __align__(16) u16 lB[4][8192];
    SETUP_8P(D_ * 2)
    const int lp = blockIdx.z, b = lp >> 1;
    const int e = eidx[lp];
    const float wk = wgate[lp];
    const char* Ab = (const char*)(A + (size_t)(b * S_ + s0 + blockIdx.y * 256) * D_);
    const char* Bb = (const char*)(Bw + (size_t)e * H_ * D_ + (size_t)(blockIdx.x * 256) * D_);
    const int NT = D_ / 32;  // 32

#define G1_STA(KT3) do { _Pragma("unroll") for (int h = 0; h < 2; ++h) \
        gload16(Ab + soff[h] + (size_t)(KT3) * 64, &lA[(KT3) & 3][h * 4096 + ldst]); } while (0)
#define G1_STB(KT3) do { _Pragma("unroll") for (int h = 0; h < 2; ++h) \
        gload16(Bb + soff[h] + (size_t)(KT3) * 64, &lB[(KT3) & 3][h * 4096 + ldst]); } while (0)

    // prologue: stage K-tiles 0..2
#pragma unroll
    for (int kt = 0; kt < 3; ++kt) { G1_STA(kt); G1_STB(kt); }
    asm volatile("s_waitcnt vmcnt(8)" ::: "memory");
    __builtin_amdgcn_s_barrier();

#pragma unroll 1
    for (int kt = 0; kt < NT - 3; ++kt)
        KTILE(kt, G1_STA(kt + 3), G1_STB(kt + 3), 8);
    KTILE(NT - 3, (void)0, (void)0, 4);
    KTILE(NT - 2, (void)0, (void)0, 0);
    KTILE(NT - 1, (void)0, (void)0, -1);
#undef G1_STA
#undef G1_STB

#pragma unroll
    for (int am = 0; am < 8; ++am)
#pragma unroll
        for (int nt = 0; nt < 4; ++nt) {
            int n = blockIdx.x * 256 + wc * 64 + nt * 16 + lr;
            float bb = b1[e * H_ + n];
#pragma unroll
            for (int r = 0; r < 4; ++r) {
                int mrow = blockIdx.y * 256 + wr * 128 + (am >> 2) * 64 + (am & 3) * 16 + quad * 4 + r;
                float v = acc[am][nt][r] + bb;
                v = v / (1.f + __expf(-v)) * wk;
                hbuf[((size_t)lp * hRows + mrow) * H_ + n] = f2bf(v);
            }
        }
}

// GEMM2: out[b] = sum_kp hbuf[b*2+kp] @ W2T[e_kp]^T + sum w*b2;  virtual K = 2*H_, ld=H_
__global__ __launch_bounds__(512) void gemm2_8p(
    const u16* __restrict__ hbuf, const u16* __restrict__ Bw,
    const float* __restrict__ b2, const int* __restrict__ eidx,
    const float* __restrict__ wgate, float* __restrict__ out,
    int s0, int hRows) {
    __shared__ __align__(16) u16 lA[4][8192];
    __shared__ __align__(16) u16 lB[4][8192];
    SETUP_8P(H_ * 2)
    const int b = blockIdx.z;
    const int e0 = eidx[b * 2], e1 = eidx[b * 2 + 1];
    const float w0 = wgate[b * 2], w1 = wgate[b * 2 + 1];
    const char* Ab0 = (const char*)(hbuf + ((size_t)(b * 2) * hRows + blockIdx.y * 256) * H_);
    const char* Ab1 = (const char*)(hbuf + ((size_t)(b * 2 + 1) * hRows + blockIdx.y * 256) * H_);
    const char* Bb0 = (const char*)(Bw + (size_t)e0 * D_ * H_ + (size_t)(blockIdx.x * 256) * H_);
    const char* Bb1 = (const char*)(Bw + (size_t)e1 * D_ * H_ + (size_t)(blockIdx.x * 256) * H_);
    const int NT = 2 * H_ / 32;  // 256

#define G2_STA(KT3) do { const int kts_ = (KT3); \
        const char* As_ = (kts_ & 128) ? Ab1 : Ab0; \
        _Pragma("unroll") for (int h = 0; h < 2; ++h) \
            gload16(As_ + soff[h] + (size_t)(kts_ & 127) * 64, &lA[kts_ & 3][h * 4096 + ldst]); } while (0)
#define G2_STB(KT3) do { const int kts_ = (KT3); \
        const char* Bs_ = (kts_ & 128) ? Bb1 : Bb0; \
        _Pragma("unroll") for (int h = 0; h < 2; ++h) \
            gload16(Bs_ + soff[h] + (size_t)(kts_ & 127) * 64, &lB[kts_ & 3][h * 4096 + ldst]); } while (0)

#pragma unroll
    for (int kt = 0; kt < 3; ++kt) { G2_STA(kt); G2_STB(kt); }
    asm volatile("s_waitcnt vmcnt(8)" ::: "memory");
    __builtin_amdgcn_s_barrier();

#pragma unroll 1
    for (int kt = 0; kt < NT - 3; ++kt)
        KTILE(kt, G2_STA(kt + 3), G2_STB(kt + 3), 8);
    KTILE(NT - 3, (void)0, (void)0, 4);
    KTILE(NT - 2, (void)0, (void)0, 0);
    KTILE(NT - 1, (void)0, (void)0, -1);
#undef G2_STA
#undef G2_STB

#pragma unroll
    for (int am = 0; am < 8; ++am)
#pragma unroll
        for (int nt = 0; nt < 4; ++nt) {
            int n = blockIdx.x * 256 + wc * 64 + nt * 16 + lr;
            float bb = w0 * b2[e0 * D_ + n] + w1 * b2[e1 * D_ + n];
#pragma unroll
            for (int r = 0; r < 4; ++r) {
                int mrow = blockIdx.y * 256 + wr * 128 + (am >> 2) * 64 + (am & 3) * 16 + quad * 4 + r;
                out[((size_t)b * S_ + s0 + mrow) * D_ + n] = acc[am][nt][r] + bb;
            }
        }
}

// ===================== old 128x128 2-phase GEMMs (tier-C fallback only) =====================
template<int BT>
__global__ __launch_bounds__(256) void gemm1_kernel(
    const void* __restrict__ A_, const void* __restrict__ Bw_,
    const float* __restrict__ b1, const int* __restrict__ eidx,
    const float* __restrict__ wgate, u16* __restrict__ hbuf,
    int s0, int hRows, int pbase) {
    __shared__ __align__(16) u16 ldsA[1024 * 8];
    __shared__ __align__(16) u16 ldsB[1024 * 8];
    int tid = threadIdx.x, lane = tid & 63, wid = tid >> 6;
    int wm = wid & 1, wn = wid >> 1, lr = lane & 15, quad = lane >> 4;
    int lp = blockIdx.z, p = pbase + lp, b = p >> 1;
    int e = eidx[p];
    float wk = wgate[p];
    size_t arow = (size_t)(b * S_ + s0 + blockIdx.y * 128);
    floatx4 acc[4][4] = {};
    for (int kk = 0; kk < D_; kk += 64) {
        if (BT == 0) {
            stage((const u16*)A_ + arow * D_ + kk, D_, ldsA, tid);
            stage((const u16*)Bw_ + (size_t)e * H_ * D_ +
                  (size_t)(blockIdx.x * 128) * D_ + kk, D_, ldsB, tid);
        } else {
            stageF((const float*)A_ + arow * D_ + kk, D_, ldsA, tid);
            stageKTF((const float*)Bw_ + (size_t)e * D_ * H_ +
                     (size_t)kk * H_ + blockIdx.x * 128, H_, ldsB, tid);
        }
        __syncthreads();
#pragma unroll
        for (int ks = 0; ks < 2; ++ks) {
            bf16x8 af[4], bfr[4];
#pragma unroll
            for (int t = 0; t < 4; ++t) {
                af[t]  = fragld(ldsA, wm * 64 + t * 16 + lr, ks * 4 + quad);
                bfr[t] = fragld(ldsB, wn * 64 + t * 16 + lr, ks * 4 + quad);
            }
#pragma unroll
            for (int mt = 0; mt < 4; ++mt)
#pragma unroll
                for (int nt = 0; nt < 4; ++nt)
                    acc[mt][nt] = __builtin_amdgcn_mfma_f32_16x16x32_bf16(
                        af[mt], bfr[nt], acc[mt][nt], 0, 0, 0);
        }
        __syncthreads();
    }
#pragma unroll
    for (int mt = 0; mt < 4; ++mt)
#pragma unroll
        for (int nt = 0; nt < 4; ++nt) {
            int n = blockIdx.x * 128 + wn * 64 + nt * 16 + lr;
            float bb = b1[e * H_ + n];
#pragma unroll
            for (int r = 0; r < 4; ++r) {
                int mrow = blockIdx.y * 128 + wm * 64 + mt * 16 + quad * 4 + r;
                float v = acc[mt][nt][r] + bb;
                v = v / (1.f + __expf(-v)) * wk;
                hbuf[((size_t)lp * hRows + mrow) * H_ + n] = f2bf(v);
            }
        }
}

template<int BT>
__global__ __launch_bounds__(256) void gemm2_kernel(
    const u16* __restrict__ hbuf, const void* __restrict__ Bw_,
    const float* __restrict__ b2, const int* __restrict__ eidx,
    const float* __restrict__ wgate, float* __restrict__ out,
    int s0, int hRows, int bbase) {
    __shared__ __align__(16) u16 ldsA[1024 * 8];
    __shared__ __align__(16) u16 ldsB[1024 * 8];
    int tid = threadIdx.x, lane = tid & 63, wid = tid >> 6;
    int wm = wid & 1, wn = wid >> 1, lr = lane & 15, quad = lane >> 4;
    int lb = blockIdx.z, b = bbase + lb;
    floatx4 acc[4][4] = {};
    for (int kp = 0; kp < 2; ++kp) {
        int e = eidx[b * 2 + kp];
        const u16* Abase = hbuf + ((size_t)(lb * 2 + kp) * hRows + blockIdx.y * 128) * H_;
        for (int kk = 0; kk < H_; kk += 64) {
            stage(Abase + kk, H_, ldsA, tid);
            if (BT == 0)
                stage((const u16*)Bw_ + (size_t)e * D_ * H_ +
                      (size_t)(blockIdx.x * 128) * H_ + kk, H_, ldsB, tid);
            else
                stageKTF((const float*)Bw_ + (size_t)e * H_ * D_ +
                         (size_t)kk * D_ + blockIdx.x * 128, D_, ldsB, tid);
            __syncthreads();
#pragma unroll
            for (int ks = 0; ks < 2; ++ks) {
                bf16x8 af[4], bfr[4];
#pragma unroll
                for (int t = 0; t < 4; ++t) {
                    af[t]  = fragld(ldsA, wm * 64 + t * 16 + lr, ks * 4 + quad);
                    bfr[t] = fragld(ldsB, wn * 64 + t * 16 + lr, ks * 4 + quad);
                }
#pragma unroll
                for (int mt = 0; mt < 4; ++mt)
#pragma unroll
                    for (int nt = 0; nt < 4; ++nt)
                        acc[mt][nt] = __builtin_amdgcn_mfma_f32_16x16x32_bf16(
                            af[mt], bfr[nt], acc[mt][nt], 0, 0, 0);
            }
            __syncthreads();
        }
    }
    int e0 = eidx[b * 2], e1 = eidx[b * 2 + 1];
    float w0 = wgate[b * 2], w1 = wgate[b * 2 + 1];
#pragma unroll
    for (int mt = 0; mt < 4; ++mt)
#pragma unroll
        for (int nt = 0; nt < 4; ++nt) {
            int n = blockIdx.x * 128 + wn * 64 + nt * 16 + lr;
            float bb = w0 * b2[e0 * D_ + n] + w1 * b2[e1 * D_ + n];
#pragma unroll
            for (int r = 0; r < 4; ++r) {
                int mrow = blockIdx.y * 128 + wm * 64 + mt * 16 + quad * 4 + r;
                out[((size_t)b * S_ + s0 + mrow) * D_ + n] = acc[mt][nt][r] + bb;
            }
        }
}

extern "C" void kernel_launch(void* const* d_in, const int* in_sizes, int n_in,
                              void* d_out, int out_size, void* d_ws, size_t ws_size,
                              hipStream_t stream) {
    const float* x   = (const float*)d_in[0];
    const float* Wg1 = (const float*)d_in[1];
    const float* bg1 = (const float*)d_in[2];
    const float* Wg2 = (const float*)d_in[3];
    const float* bg2 = (const float*)d_in[4];
    const float* W1  = (const float*)d_in[5];
    const float* b1  = (const float*)d_in[6];
    const float* W2  = (const float*)d_in[7];
    const float* b2  = (const float*)d_in[8];
    float* out = (float*)d_out;
    char* ws = (char*)d_ws;

    float* ri    = (float*)ws;                 // 32 KB
    float* gh    = (float*)(ws + 32768);       // 32 KB
    float* wgate = (float*)(ws + 65536);       // 64 B
    int*   eidx  = (int*)(ws + 65792);         // 64 B
    float* part  = (float*)(ws + 131072);      // 256 KB mean partials

    const size_t base = (size_t)1 << 20;                  // 1 MiB small-buffer region
    const size_t szXb = (size_t)B_ * S_ * D_ * 2;         // 32 MiB bf16 x
    const size_t szW  = (size_t)E_ * D_ * H_ * 2;         // 64 MiB per bf16 weight set
    const size_t rowB = (size_t)H_ * 2;                   // 8 KiB per hbuf row

    mean1_kernel<<<dim3(B_ * 4, 8), 256, 0, stream>>>(x, part);
    mean2_kernel<<<dim3(B_ * 4), 256, 0, stream>>>(part, ri);
    gate1_kernel<<<dim3(B_ * 4), 256, 0, stream>>>(ri, Wg1, bg1, gh);
    gate2_kernel<<<1, 64, 0, stream>>>(gh, Wg2, bg2, wgate, eidx, out);

    auto clampSc256 = [](long v) -> int {
        long s = v & ~255L;
        if (s > S_) s = S_;
        if (s < 256) s = 256;
        return (int)s;
    };
    auto clampSc128 = [](long v) -> int {
        long s = v & ~127L;
        if (s > S_) s = S_;
        if (s < 128) s = 128;
        return (int)s;
    };

    if (ws_size >= base + szXb + 2 * szW + (size_t)16 * 256 * rowB) {
        // ---- Tier A: bf16 x + transposed bf16 weights + hbuf; 256x256 8-phase GEMMs ----
        u16* xb   = (u16*)(ws + base);
        u16* W1T  = (u16*)(ws + base + szXb);
        u16* W2T  = (u16*)(ws + base + szXb + szW);
        u16* hbuf = (u16*)(ws + base + szXb + 2 * szW);
        int Sc = clampSc256((long)((ws_size - base - szXb - 2 * szW) / ((size_t)16 * rowB)));
        convx_kernel<<<dim3((B_ * S_ * D_) / (256 * 8)), 256, 0, stream>>>(x, xb);
        convT_kernel<<<dim3(H_ / 64, D_ / 64, E_), 256, 0, stream>>>(W1, W1T, D_, H_);
        convT_kernel<<<dim3(D_ / 64, H_ / 64, E_), 256, 0, stream>>>(W2, W2T, H_, D_);
        for (int s0 = 0; s0 < S_; s0 += Sc) {
            int rows = (S_ - s0 < Sc) ? (S_ - s0) : Sc;
            gemm1_8p<<<dim3(H_ / 256, rows / 256, B_ * 2), 512, 0, stream>>>(
                xb, W1T, b1, eidx, wgate, hbuf, s0, Sc);
            gemm2_8p<<<dim3(D_ / 256, rows / 256, B_), 512, 0, stream>>>(
                hbuf, W2T, b2, eidx, wgate, out, s0, Sc);
        }
    } else {
        // ---- Tier C: no conversion buffers; stage fp32->bf16 through LDS (old path) ----
        u16* hbuf = (u16*)(ws + base);
        long avail = (long)ws_size - (long)base;
        if (avail < 0) avail = 0;
        int Sc = clampSc128(avail / (long)(2 * rowB));
        for (int b = 0; b < B_; ++b) {
            for (int s0 = 0; s0 < S_; s0 += Sc) {
                int rows = (S_ - s0 < Sc) ? (S_ - s0) : Sc;
                gemm1_kernel<1><<<dim3(H_ / 128, rows / 128, 2), 256, 0, stream>>>(
                    x, W1, b1, eidx, wgate, hbuf, s0, Sc, b * 2);
                gemm2_kernel<1><<<dim3(D_ / 128, rows / 128, 1), 256, 0, stream>>>(
                    hbuf, W2, b2, eidx, wgate, out, s0, Sc, b);
            }
        }
    }
}